// Round 1
// baseline (237.731 us; speedup 1.0000x reference)
//
#include <hip/hip_runtime.h>

#define BB 64
#define JJ 24
#define TT 2048
#define NELEM (BB*JJ*6*TT)          // 18,874,368
#define NVEL  ((long long)BB*JJ*6*(TT-1))

__device__ __forceinline__ void block_reduce2(float& a, float& b) {
    // wave-64 butterfly
    #pragma unroll
    for (int off = 32; off > 0; off >>= 1) {
        a += __shfl_down(a, off);
        b += __shfl_down(b, off);
    }
    __shared__ float sa[4], sb[4];          // 256 threads = 4 waves
    const int lane = threadIdx.x & 63;
    const int wid  = threadIdx.x >> 6;
    if (lane == 0) { sa[wid] = a; sb[wid] = b; }
    __syncthreads();
    if (threadIdx.x == 0) {
        const int nw = blockDim.x >> 6;
        for (int w = 1; w < nw; ++w) { a += sa[w]; b += sb[w]; }
    }
}

// Pass over pred/target: recon sum-of-squares + velocity-diff sum-of-squares.
__global__ __launch_bounds__(256) void recon_vel_kernel(
        const float* __restrict__ pred, const float* __restrict__ targ,
        double* __restrict__ acc) {
    float recon = 0.f, vel = 0.f;
    const int n4 = NELEM / 4;
    for (int i = blockIdx.x * blockDim.x + threadIdx.x; i < n4;
         i += gridDim.x * blockDim.x) {
        const float4 p = reinterpret_cast<const float4*>(pred)[i];
        const float4 g = reinterpret_cast<const float4*>(targ)[i];
        const float d0 = p.x - g.x, d1 = p.y - g.y, d2 = p.z - g.z, d3 = p.w - g.w;
        recon += d0*d0 + d1*d1 + d2*d2 + d3*d3;
        const float e01 = d1 - d0, e12 = d2 - d1, e23 = d3 - d2;
        vel += e01*e01 + e12*e12 + e23*e23;
        const int e  = i * 4;
        const int t0 = e & (TT - 1);        // position in row; T=2048 pow2
        if (t0 != 0) {
            const float dm1 = pred[e - 1] - targ[e - 1];   // cache-hit reload
            const float b0  = d0 - dm1;
            vel += b0 * b0;
        }
    }
    block_reduce2(recon, vel);
    if (threadIdx.x == 0) {
        atomicAdd(&acc[0], (double)recon);
        atomicAdd(&acc[1], (double)vel);
    }
}

// Foot-contact loss: one block per (b, foot) row.
__global__ __launch_bounds__(256) void foot_kernel(
        const float* __restrict__ jp, double* __restrict__ acc) {
    const int FI[4] = {7, 8, 10, 11};
    const int bf = blockIdx.x;              // 0..255
    const int b  = bf >> 2;
    const int j  = FI[bf & 3];
    const float* __restrict__ xrow = jp + ((size_t)(b * JJ + j) * 3 + 0) * TT;
    const float* __restrict__ yrow = xrow + TT;
    const float* __restrict__ zrow = xrow + 2 * TT;
    float lsum = 0.f, csum = 0.f;
    for (int t = threadIdx.x + 1; t < TT; t += blockDim.x) {
        const float x1 = xrow[t], x0 = xrow[t - 1];
        const float y1 = yrow[t], y0 = yrow[t - 1];
        const float z1 = zrow[t], z0 = zrow[t - 1];
        const float w1 = 1.f / (1.f + expf(-(0.05f - y1) * 20.f));
        const float w0 = 1.f / (1.f + expf(-(0.05f - y0) * 20.f));
        const float cw = 0.5f * (w1 + w0);
        const float vx = x1 - x0, vz = z1 - z0;
        lsum += (vx * vx + vz * vz) * cw;
        csum += cw;
    }
    block_reduce2(lsum, csum);
    if (threadIdx.x == 0) {
        atomicAdd(&acc[2], (double)lsum);
        atomicAdd(&acc[3], (double)csum);
    }
}

__global__ void finalize_kernel(const double* __restrict__ acc,
                                float* __restrict__ out) {
    const double recon = acc[0] / (double)NELEM;
    const double vel   = acc[1] / (double)NVEL;
    const double foot  = acc[2] / (acc[3] + 1e-8);
    out[0] = (float)(recon + 0.2 * vel + 0.1 * foot);
}

extern "C" void kernel_launch(void* const* d_in, const int* in_sizes, int n_in,
                              void* d_out, int out_size, void* d_ws, size_t ws_size,
                              hipStream_t stream) {
    const float* pred = (const float*)d_in[0];
    const float* targ = (const float*)d_in[1];
    const float* jp   = (const float*)d_in[2];
    float* out  = (float*)d_out;
    double* acc = (double*)d_ws;

    hipMemsetAsync(d_ws, 0, 4 * sizeof(double), stream);
    recon_vel_kernel<<<2048, 256, 0, stream>>>(pred, targ, acc);
    foot_kernel<<<256, 256, 0, stream>>>(jp, acc);
    finalize_kernel<<<1, 1, 0, stream>>>(acc, out);
}

// Round 2
// 218.586 us; speedup vs baseline: 1.0876x; 1.0876x over previous
//
#include <hip/hip_runtime.h>

#define BB 64
#define JJ 24
#define TT 2048
#define NELEM (BB*JJ*6*TT)              // 18,874,368 floats
#define NVEL  ((long long)BB*JJ*6*(TT-1))
#define NCHUNK (NELEM/4)                // 4,718,592 float4
#define FOOT_BLOCKS 256
#define RGRID 2048
#define RTHREADS (RGRID*256)            // 524,288 -> 9 chunks/thread exactly

__device__ __forceinline__ void block_reduce2(float& a, float& b) {
    #pragma unroll
    for (int off = 32; off > 0; off >>= 1) {
        a += __shfl_down(a, off);
        b += __shfl_down(b, off);
    }
    __shared__ float sa[4], sb[4];
    const int lane = threadIdx.x & 63;
    const int wid  = threadIdx.x >> 6;
    if (lane == 0) { sa[wid] = a; sb[wid] = b; }
    __syncthreads();
    if (threadIdx.x == 0) {
        for (int w = 1; w < 4; ++w) { a += sa[w]; b += sb[w]; }
    }
}

__device__ __forceinline__ float sigm(float y) {
    return 1.f / (1.f + __expf(-(0.05f - y) * 20.f));
}

__global__ __launch_bounds__(256) void fused_kernel(
        const float* __restrict__ pred, const float* __restrict__ targ,
        const float* __restrict__ jp, double* __restrict__ acc) {

    if (blockIdx.x < FOOT_BLOCKS) {
        // ---------------- foot-contact loss: one block per (b, foot) ----------
        const int FI[4] = {7, 8, 10, 11};
        const int bf = blockIdx.x;
        const int b  = bf >> 2;
        const int j  = FI[bf & 3];
        const float* __restrict__ xrow = jp + ((size_t)(b * JJ + j) * 3) * TT;
        const float* __restrict__ yrow = xrow + TT;
        const float* __restrict__ zrow = xrow + 2 * TT;
        const float4* __restrict__ x4 = reinterpret_cast<const float4*>(xrow);
        const float4* __restrict__ y4 = reinterpret_cast<const float4*>(yrow);
        const float4* __restrict__ z4 = reinterpret_cast<const float4*>(zrow);

        float lsum = 0.f, csum = 0.f;
        #pragma unroll
        for (int cc = 0; cc < 2; ++cc) {
            const int c = threadIdx.x + cc * 256;         // chunk: t in [4c, 4c+4)
            const float4 xv = x4[c], yv = y4[c], zv = z4[c];
            float x0 = 0.f, y0 = 0.f, z0 = 0.f;
            if (c > 0) { x0 = xrow[4*c-1]; y0 = yrow[4*c-1]; z0 = zrow[4*c-1]; }
            const float w0 = sigm(y0),  w1 = sigm(yv.x), w2 = sigm(yv.y),
                        w3 = sigm(yv.z), w4 = sigm(yv.w);
            auto term = [&](float x1, float xp, float z1, float zp,
                            float wa, float wb) {
                const float cw = 0.5f * (wa + wb);
                const float vx = x1 - xp, vz = z1 - zp;
                lsum += (vx * vx + vz * vz) * cw;
                csum += cw;
            };
            if (c > 0) term(xv.x, x0, zv.x, z0, w1, w0);
            term(xv.y, xv.x, zv.y, zv.x, w2, w1);
            term(xv.z, xv.y, zv.z, zv.y, w3, w2);
            term(xv.w, xv.z, zv.w, zv.z, w4, w3);
        }
        block_reduce2(lsum, csum);
        if (threadIdx.x == 0) {
            atomicAdd(&acc[2], (double)lsum);
            atomicAdd(&acc[3], (double)csum);
        }
    } else {
        // ---------------- recon + vel over pred/target -----------------------
        const float4* __restrict__ pred4 = reinterpret_cast<const float4*>(pred);
        const float4* __restrict__ targ4 = reinterpret_cast<const float4*>(targ);
        const int tid = (blockIdx.x - FOOT_BLOCKS) * 256 + threadIdx.x;
        float recon = 0.f, vel = 0.f;

        auto proc = [&](const float4& p, const float4& g, int i) {
            const float d0 = p.x - g.x, d1 = p.y - g.y,
                        d2 = p.z - g.z, d3 = p.w - g.w;
            recon += d0*d0 + d1*d1 + d2*d2 + d3*d3;
            const float e01 = d1 - d0, e12 = d2 - d1, e23 = d3 - d2;
            vel += e01*e01 + e12*e12 + e23*e23;
            // boundary term: d at element e-1 is lane-1's d3 (same chunk idx)
            const float dprev = __shfl_up(d3, 1);
            const int e = i * 4;
            if (e & (TT - 1)) {
                float dm1 = dprev;
                if ((threadIdx.x & 63) == 0)
                    dm1 = pred[e - 1] - targ[e - 1];      // L1/L2 hit
                const float b0 = d0 - dm1;
                vel += b0 * b0;
            }
        };

        #pragma unroll
        for (int grp = 0; grp < 3; ++grp) {
            const int i0 = tid + grp * 3 * RTHREADS;
            const float4 P0 = pred4[i0];
            const float4 G0 = targ4[i0];
            const float4 P1 = pred4[i0 + RTHREADS];
            const float4 G1 = targ4[i0 + RTHREADS];
            const float4 P2 = pred4[i0 + 2 * RTHREADS];
            const float4 G2 = targ4[i0 + 2 * RTHREADS];
            proc(P0, G0, i0);
            proc(P1, G1, i0 + RTHREADS);
            proc(P2, G2, i0 + 2 * RTHREADS);
        }
        block_reduce2(recon, vel);
        if (threadIdx.x == 0) {
            atomicAdd(&acc[0], (double)recon);
            atomicAdd(&acc[1], (double)vel);
        }
    }
}

__global__ void finalize_kernel(const double* __restrict__ acc,
                                float* __restrict__ out) {
    const double recon = acc[0] / (double)NELEM;
    const double vel   = acc[1] / (double)NVEL;
    const double foot  = acc[2] / (acc[3] + 1e-8);
    out[0] = (float)(recon + 0.2 * vel + 0.1 * foot);
}

extern "C" void kernel_launch(void* const* d_in, const int* in_sizes, int n_in,
                              void* d_out, int out_size, void* d_ws, size_t ws_size,
                              hipStream_t stream) {
    const float* pred = (const float*)d_in[0];
    const float* targ = (const float*)d_in[1];
    const float* jp   = (const float*)d_in[2];
    float* out  = (float*)d_out;
    double* acc = (double*)d_ws;

    hipMemsetAsync(d_ws, 0, 4 * sizeof(double), stream);
    fused_kernel<<<RGRID + FOOT_BLOCKS, 256, 0, stream>>>(pred, targ, jp, acc);
    finalize_kernel<<<1, 1, 0, stream>>>(acc, out);
}

// Round 4
// 199.008 us; speedup vs baseline: 1.1946x; 1.0984x over previous
//
#include <hip/hip_runtime.h>

#define BB 64
#define JJ 24
#define TT 2048
#define NELEM (BB*JJ*6*TT)              // 18,874,368 floats
#define NVEL  ((long long)BB*JJ*6*(TT-1))
#define FOOT_BLOCKS 256
#define RGRID 2048
#define RTHREADS (RGRID*256)            // 524,288 threads -> 9 chunks each
#define NBLK (RGRID + FOOT_BLOCKS)      // 2304 partial slots

__device__ __forceinline__ void block_reduce2(float& a, float& b) {
    #pragma unroll
    for (int off = 32; off > 0; off >>= 1) {
        a += __shfl_down(a, off);
        b += __shfl_down(b, off);
    }
    __shared__ float sa[4], sb[4];
    const int lane = threadIdx.x & 63;
    const int wid  = threadIdx.x >> 6;
    if (lane == 0) { sa[wid] = a; sb[wid] = b; }
    __syncthreads();
    if (threadIdx.x == 0) {
        for (int w = 1; w < 4; ++w) { a += sa[w]; b += sb[w]; }
    }
}

__device__ __forceinline__ float sigm(float y) {
    return 1.f / (1.f + __expf(-(0.05f - y) * 20.f));
}

// parts[blockIdx.x] = (recon, vel) for recon blocks, (lsum, csum) for foot blocks.
__global__ __launch_bounds__(256) void fused_kernel(
        const float* __restrict__ pred, const float* __restrict__ targ,
        const float* __restrict__ jp, double2* __restrict__ parts) {

    if (blockIdx.x < FOOT_BLOCKS) {
        // ---------------- foot-contact loss: one block per (b, foot) ----------
        const int FI[4] = {7, 8, 10, 11};
        const int bf = blockIdx.x;
        const int b  = bf >> 2;
        const int j  = FI[bf & 3];
        const float* __restrict__ xrow = jp + ((size_t)(b * JJ + j) * 3) * TT;
        const float* __restrict__ yrow = xrow + TT;
        const float* __restrict__ zrow = xrow + 2 * TT;
        const float4* __restrict__ x4 = reinterpret_cast<const float4*>(xrow);
        const float4* __restrict__ y4 = reinterpret_cast<const float4*>(yrow);
        const float4* __restrict__ z4 = reinterpret_cast<const float4*>(zrow);

        float lsum = 0.f, csum = 0.f;
        #pragma unroll
        for (int cc = 0; cc < 2; ++cc) {
            const int c = threadIdx.x + cc * 256;         // chunk: t in [4c, 4c+4)
            const float4 xv = x4[c], yv = y4[c], zv = z4[c];
            float x0 = 0.f, y0 = 0.f, z0 = 0.f;
            if (c > 0) { x0 = xrow[4*c-1]; y0 = yrow[4*c-1]; z0 = zrow[4*c-1]; }
            const float w0 = sigm(y0),  w1 = sigm(yv.x), w2 = sigm(yv.y),
                        w3 = sigm(yv.z), w4 = sigm(yv.w);
            auto term = [&](float x1, float xp, float z1, float zp,
                            float wa, float wb) {
                const float cw = 0.5f * (wa + wb);
                const float vx = x1 - xp, vz = z1 - zp;
                lsum += (vx * vx + vz * vz) * cw;
                csum += cw;
            };
            if (c > 0) term(xv.x, x0, zv.x, z0, w1, w0);
            term(xv.y, xv.x, zv.y, zv.x, w2, w1);
            term(xv.z, xv.y, zv.z, zv.y, w3, w2);
            term(xv.w, xv.z, zv.w, zv.z, w4, w3);
        }
        block_reduce2(lsum, csum);
        if (threadIdx.x == 0)
            parts[blockIdx.x] = make_double2((double)lsum, (double)csum);
    } else {
        // ---------------- recon + vel over pred/target -----------------------
        const float4* __restrict__ pred4 = reinterpret_cast<const float4*>(pred);
        const float4* __restrict__ targ4 = reinterpret_cast<const float4*>(targ);
        const int tid = (blockIdx.x - FOOT_BLOCKS) * 256 + threadIdx.x;
        float recon = 0.f, vel = 0.f;

        auto proc = [&](const float4& p, const float4& g, int i) {
            const float d0 = p.x - g.x, d1 = p.y - g.y,
                        d2 = p.z - g.z, d3 = p.w - g.w;
            recon += d0*d0 + d1*d1 + d2*d2 + d3*d3;
            const float e01 = d1 - d0, e12 = d2 - d1, e23 = d3 - d2;
            vel += e01*e01 + e12*e12 + e23*e23;
            // boundary term: d at element e-1 is lane-1's d3 (same chunk idx)
            const float dprev = __shfl_up(d3, 1);
            const int e = i * 4;
            if (e & (TT - 1)) {
                float dm1 = dprev;
                if ((threadIdx.x & 63) == 0)
                    dm1 = pred[e - 1] - targ[e - 1];      // L1/L2 hit
                const float b0 = d0 - dm1;
                vel += b0 * b0;
            }
        };

        #pragma unroll
        for (int grp = 0; grp < 3; ++grp) {
            const int i0 = tid + grp * 3 * RTHREADS;
            const float4 P0 = pred4[i0];
            const float4 G0 = targ4[i0];
            const float4 P1 = pred4[i0 + RTHREADS];
            const float4 G1 = targ4[i0 + RTHREADS];
            const float4 P2 = pred4[i0 + 2 * RTHREADS];
            const float4 G2 = targ4[i0 + 2 * RTHREADS];
            proc(P0, G0, i0);
            proc(P1, G1, i0 + RTHREADS);
            proc(P2, G2, i0 + 2 * RTHREADS);
        }
        block_reduce2(recon, vel);
        if (threadIdx.x == 0)
            parts[blockIdx.x] = make_double2((double)recon, (double)vel);
    }
}

// Single wave reduces all 2304 double2 partials and writes the scalar loss.
__global__ __launch_bounds__(64) void finalize_kernel(
        const double2* __restrict__ parts, float* __restrict__ out) {
    double foot_l = 0.0, foot_c = 0.0, recon = 0.0, vel = 0.0;
    for (int i = threadIdx.x; i < NBLK; i += 64) {
        const double2 v = parts[i];
        if (i < FOOT_BLOCKS) { foot_l += v.x; foot_c += v.y; }
        else                 { recon  += v.x; vel    += v.y; }
    }
    #pragma unroll
    for (int off = 32; off > 0; off >>= 1) {
        recon  += __shfl_down(recon,  off);
        vel    += __shfl_down(vel,    off);
        foot_l += __shfl_down(foot_l, off);
        foot_c += __shfl_down(foot_c, off);
    }
    if (threadIdx.x == 0) {
        const double r = recon / (double)NELEM;
        const double v = vel   / (double)NVEL;
        const double f = foot_l / (foot_c + 1e-8);
        out[0] = (float)(r + 0.2 * v + 0.1 * f);
    }
}

extern "C" void kernel_launch(void* const* d_in, const int* in_sizes, int n_in,
                              void* d_out, int out_size, void* d_ws, size_t ws_size,
                              hipStream_t stream) {
    const float* pred = (const float*)d_in[0];
    const float* targ = (const float*)d_in[1];
    const float* jp   = (const float*)d_in[2];
    float* out     = (float*)d_out;
    double2* parts = (double2*)d_ws;

    fused_kernel<<<NBLK, 256, 0, stream>>>(pred, targ, jp, parts);
    finalize_kernel<<<1, 64, 0, stream>>>(parts, out);
}